// Round 3
// baseline (1208.311 us; speedup 1.0000x reference)
//
#include <hip/hip_runtime.h>
#include <hip/hip_cooperative_groups.h>

namespace cg = cooperative_groups;
typedef unsigned long long ull;

// Problem constants
#define N_CELLS   3872
#define NCLS      80
#define NFLAT     309760        // 3872*80
#define FH        128
#define FW        192
#define HW        24576         // 128*192
#define WORDS     384           // HW/64
#define PRE       500
#define OH        512
#define OW        768
#define OPIX      393216        // 512*768
#define MAXI      100
#define NBUCKET   16384
#define COLCAP    4096

// Workspace byte offsets (all 8B aligned)
#define OFF_HIST      0          // u32[16384]
#define OFF_CNT       65536      // u32[16]   [0]=collect count, [1]=bucket B
#define OFF_KEYBUF    65600      // u64[4096]
#define OFF_EGIDX     98368      // i32[512]
#define OFF_ELABEL    100416     // i32[512]
#define OFF_ECOUNT    102464     // i32[512]
#define OFF_TKSCORE   104512     // f32[512]
#define OFF_ESCORE1   106560     // f64[512]
#define OFF_ORDER1    110656     // i32[512]
#define OFF_SCORES    112704     // f64[512]  sorted-1 scores
#define OFF_COMP      116800     // f32[512]
#define OFF_ECI       118848     // f64[512]  (unused now; eci computed inline)
#define OFF_NS        122944     // f64[512]  post-NMS scores (sorted-1 space)
#define OFF_FINALE    127040     // i32[128]
#define OFF_BOXESI    127552     // i32[400]
#define OFF_PACKED    129152     // u64[500*384]
#define OFF_DMAT      1665152    // f32[500*500]
// total ~2.67 MB

// cooperative grid: 512 blocks x 256 threads = 2 blocks/CU on 256 CUs.
// LDS 33 KB/block (x2 = 66 KB < 160), VGPR capped by launch_bounds(256,2).
#define GRID_BLOCKS 512
#define NTHR        256
#define GSZ         (GRID_BLOCKS * NTHR)   // 131072 threads

// upsample decomposition: 24 x-chunks per f, 100 f's = 2400 virtual blocks
#define UPS_BLOCKS        24
#define GROUPS_PER_BLOCK  4096    // (OPIX/4) / UPS_BLOCKS
#define UPS_ITERS         16      // GROUPS_PER_BLOCK / 256

__device__ __forceinline__ float stride_of(int g) {
    return (g < 2896) ? 8.0f : (g < 3472) ? 16.0f : 32.0f;
}

__device__ __forceinline__ int bucket_of(float v) {
    int b = (int)((v - 0.1f) * (16384.0f / 0.9f));
    return min(max(b, 0), NBUCKET - 1);
}

// deposit 16 low bits of x to every 4th bit position of a u64
__device__ __forceinline__ ull spread4(unsigned x) {
    ull v = (ull)(x & 0xFFFFu);
    v = (v | (v << 24)) & 0x000000FF000000FFull;
    v = (v | (v << 12)) & 0x000F000F000F000Full;
    v = (v | (v << 6))  & 0x0303030303030303ull;
    v = (v | (v << 3))  & 0x1111111111111111ull;
    return v;
}

__device__ __forceinline__ bool before_key(ull as, int ai, ull bs, int bi) {
    return (as > bs) || (as == bs && ai < bi);
}

// one 16x16 dmat tile (bi,bj); identical math to the standalone k_dmat, plus
// comp[j] accumulation via atomicMax (bit-max == float max for non-negatives).
__device__ void dmat_tile(int bi, int bj, int t,
                          const ull* __restrict__ packed,
                          const int* __restrict__ order1,
                          const int* __restrict__ e_count,
                          const int* __restrict__ e_label,
                          float* __restrict__ dmat,
                          float* __restrict__ comp,
                          ull (*A)[65], ull (*B)[65]) {
    int r = t >> 4, c = t & 15;
    int i = bi * 16 + r, j = bj * 16 + c;
    if (bi > bj) {  // whole tile lower triangle -> zeros, no LDS use
        if (i < PRE && j < PRE) dmat[i * PRE + j] = 0.0f;
        return;
    }
    int oi = (i < PRE) ? order1[i] : -1;
    int oj = (j < PRE) ? order1[j] : -1;
    long long inter = 0;
    for (int ch = 0; ch < 6; ch++) {
        for (int l = t; l < 1024; l += NTHR) {
            int rr = l >> 6, ww = l & 63;
            int ii = bi * 16 + rr;
            int o = (ii < PRE) ? order1[ii] : -1;
            A[rr][ww] = (o >= 0) ? packed[(size_t)o * WORDS + ch * 64 + ww] : 0ull;
            int jj = bj * 16 + rr;
            int o2 = (jj < PRE) ? order1[jj] : -1;
            B[rr][ww] = (o2 >= 0) ? packed[(size_t)o2 * WORDS + ch * 64 + ww] : 0ull;
        }
        __syncthreads();
        #pragma unroll
        for (int w = 0; w < 64; w++) inter += __popcll(A[r][w] & B[c][w]);
        __syncthreads();
    }
    if (i < PRE && j < PRE) {
        float d = 0.0f;
        if (i < j && e_label[oi] == e_label[oj]) {
            double un = (double)(e_count[oi] + e_count[oj]) - (double)inter;
            double iou = (double)inter / fmax(un, 1e-6);
            d = (float)iou;
        }
        dmat[i * PRE + j] = d;
        if (d > 0.0f) atomicMax((unsigned*)(comp + j), __float_as_uint(d));
    }
}

__global__ __launch_bounds__(256, 2) void mega(const float* __restrict__ cate,
                                               const float* __restrict__ seg,
                                               float* __restrict__ out,
                                               char* __restrict__ ws) {
    cg::grid_group g = cg::this_grid();
    const int b = blockIdx.x;
    const int t = threadIdx.x;
    const int gid = b * NTHR + t;
    const int lane = t & 63, wv = t >> 6;

    unsigned* hist      = (unsigned*)(ws + OFF_HIST);
    unsigned* counters  = (unsigned*)(ws + OFF_CNT);
    ull* keybuf         = (ull*)(ws + OFF_KEYBUF);
    int* e_gidx         = (int*)(ws + OFF_EGIDX);
    int* e_label        = (int*)(ws + OFF_ELABEL);
    int* e_count        = (int*)(ws + OFF_ECOUNT);
    float* tk_score     = (float*)(ws + OFF_TKSCORE);
    double* e_score1    = (double*)(ws + OFF_ESCORE1);
    int* order1         = (int*)(ws + OFF_ORDER1);
    double* score_s     = (double*)(ws + OFF_SCORES);
    float* comp         = (float*)(ws + OFF_COMP);
    double* ns          = (double*)(ws + OFF_NS);
    int* final_e        = (int*)(ws + OFF_FINALE);
    int* boxes_i        = (int*)(ws + OFF_BOXESI);
    ull* packed         = (ull*)(ws + OFF_PACKED);
    float* dmat         = (float*)(ws + OFF_DMAT);

    __shared__ __align__(16) unsigned char smem[33024];

    // ---------------- P0: init ----------------
    if (gid < NBUCKET) hist[gid] = 0u;
    if (gid < 16) counters[gid] = 0u;
    if (gid < MAXI) {
        boxes_i[4*gid+0] = OW;
        boxes_i[4*gid+1] = OH;
        boxes_i[4*gid+2] = 0;
        boxes_i[4*gid+3] = 0;
    }
    if (gid < PRE) comp[gid] = 0.0f;   // atomicMax accumulator
    g.sync();

    // ---------------- P1: histogram ----------------
    if (gid < NFLAT / 4) {
        float4 v = ((const float4*)cate)[gid];
        if (v.x > 0.1f) atomicAdd(&hist[bucket_of(v.x)], 1u);
        if (v.y > 0.1f) atomicAdd(&hist[bucket_of(v.y)], 1u);
        if (v.z > 0.1f) atomicAdd(&hist[bucket_of(v.z)], 1u);
        if (v.w > 0.1f) atomicAdd(&hist[bucket_of(v.w)], 1u);
    }
    g.sync();

    // ---------------- P2: findB (block 0) ----------------
    // B = max b with suffix_count(b) >= PRE (0 if total < PRE).
    if (b == 0) {
        unsigned* part = (unsigned*)smem;          // [256]
        int* smax = (int*)(smem + 1024);
        if (t == 0) *smax = -1;
        int base = t * 64;
        unsigned s = 0;
        for (int k = 0; k < 64; k++) s += hist[base + k];
        part[t] = s;
        __syncthreads();
        for (int off = 1; off < 256; off <<= 1) {   // inclusive suffix scan
            unsigned v = part[t] + ((t + off < 256) ? part[t + off] : 0u);
            __syncthreads();
            part[t] = v;
            __syncthreads();
        }
        unsigned cum = part[t] - s;                 // suffix of chunks above t
        int cand = -1;
        for (int k = 63; k >= 0; k--) {
            cum += hist[base + k];
            if (cand < 0 && cum >= (unsigned)PRE) cand = base + k;
        }
        if (cand >= 0) atomicMax(smax, cand);
        __syncthreads();
        if (t == 0 && *smax >= 0) counters[1] = (unsigned)*smax;
    }
    g.sync();

    // ---------------- P3: collect ----------------
    if (gid < NFLAT / 4) {
        float4 v = ((const float4*)cate)[gid];
        int B = (int)counters[1];
        int base = 4 * gid;
        float vv[4] = {v.x, v.y, v.z, v.w};
        #pragma unroll
        for (int c = 0; c < 4; c++) {
            float f = vv[c];
            if (f > 0.1f && bucket_of(f) >= B) {
                unsigned pos = atomicAdd(&counters[0], 1u);
                if (pos < COLCAP) {
                    unsigned fb = __float_as_uint(f);
                    unsigned idx = (unsigned)(base + c);
                    keybuf[pos] = ((ull)fb << 32) | (ull)(0xFFFFFFFFu - idx);
                }
            }
        }
    }
    g.sync();

    // ---------------- P4: sort collected, emit top-500 (block 0) ----------------
    // Keys embed the index -> strict total order -> sorted result is unique
    // regardless of network/thread mapping. Zeros pad to the tail.
    if (b == 0) {
        ull* kk = (ull*)smem;                      // up to 4096 x 8B = 32 KB
        unsigned cnt = counters[0];
        if (cnt > COLCAP) cnt = COLCAP;
        int m = 512;
        while (m < (int)cnt) m <<= 1;
        for (int i = t; i < m; i += NTHR) kk[i] = (i < (int)cnt) ? keybuf[i] : 0ull;
        __syncthreads();
        for (int sz = 2; sz <= m; sz <<= 1) {
            for (int j = sz >> 1; j > 0; j >>= 1) {
                for (int i = t; i < m; i += NTHR) {
                    int ixj = i ^ j;
                    if (ixj > i) {
                        bool up = ((i & sz) == 0);
                        ull a = kk[i], bk = kk[ixj];
                        bool sw = up ? (a < bk) : (a > bk);   // descending
                        if (sw) { kk[i] = bk; kk[ixj] = a; }
                    }
                }
                __syncthreads();
            }
        }
        for (int i = t; i < PRE; i += NTHR) {
            ull key = kk[i];
            if (key == 0ull) {
                e_gidx[i] = 0; e_label[i] = 0; tk_score[i] = -1.0f;
            } else {
                unsigned idx = 0xFFFFFFFFu - (unsigned)(key & 0xFFFFFFFFull);
                e_gidx[i] = (int)(idx / NCLS);
                e_label[i] = (int)(idx % NCLS);
                tk_score[i] = __uint_as_float((unsigned)(key >> 32));
            }
        }
    }
    g.sync();

    // ---------------- P5: mask stats + bit-pack (blocks 0..499) ----------------
    if (b < PRE) {
        int e = b;
        const float4* row4 = (const float4*)(seg + (size_t)e_gidx[e] * HW);
        double* ssum = (double*)smem;              // [4]
        int* scnt = (int*)(smem + 32);             // [4]
        int w = lane >> 4;
        int sh = 16 * w;
        double lsum = 0.0;
        int lcnt = 0;
        #pragma unroll 4
        for (int k = 0; k < 24; k++) {
            int p4 = t + k * 256;
            float4 v = row4[p4];
            unsigned nib = (v.x > 0.5f ? 1u : 0u) | (v.y > 0.5f ? 2u : 0u) |
                           (v.z > 0.5f ? 4u : 0u) | (v.w > 0.5f ? 8u : 0u);
            ull b0 = __ballot(nib & 1u);
            ull b1 = __ballot(nib & 2u);
            ull b2 = __ballot(nib & 4u);
            ull b3 = __ballot(nib & 8u);
            ull word = spread4((unsigned)(b0 >> sh))
                     | (spread4((unsigned)(b1 >> sh)) << 1)
                     | (spread4((unsigned)(b2 >> sh)) << 2)
                     | (spread4((unsigned)(b3 >> sh)) << 3);
            if ((lane & 15) == 0) packed[(size_t)e * WORDS + (k * 16 + wv * 4 + w)] = word;
            if (v.x > 0.5f) lsum += (double)v.x;
            if (v.y > 0.5f) lsum += (double)v.y;
            if (v.z > 0.5f) lsum += (double)v.z;
            if (v.w > 0.5f) lsum += (double)v.w;
            lcnt += __popc(nib);
        }
        for (int off = 32; off > 0; off >>= 1) {
            lsum += __shfl_down(lsum, off);
            lcnt += __shfl_down(lcnt, off);
        }
        if (lane == 0) { ssum[wv] = lsum; scnt[wv] = lcnt; }
        __syncthreads();
        if (t == 0) {
            double sum = ssum[0] + ssum[1] + ssum[2] + ssum[3];
            int cnt = scnt[0] + scnt[1] + scnt[2] + scnt[3];
            double segsc = sum / (double)max(cnt, 1);
            float sc = tk_score[e];
            bool keep = (sc > 0.1f) && ((float)cnt > stride_of(e_gidx[e]));
            e_count[e] = cnt;
            e_score1[e] = keep ? ((double)sc * segsc) : 0.0;
        }
    }
    g.sync();

    // ---------------- P6: sort1 (block 0), emit permutation ----------------
    if (b == 0) {
        ull* sb = (ull*)smem;                      // [512]
        int* si = (int*)(smem + 4096);             // [512]
        for (int i = t; i < 512; i += NTHR) {
            sb[i] = (i < PRE) ? (ull)__double_as_longlong(e_score1[i]) : 0ull;
            si[i] = i;
        }
        __syncthreads();
        for (int sz = 2; sz <= 512; sz <<= 1) {
            for (int j = sz >> 1; j > 0; j >>= 1) {
                for (int i = t; i < 512; i += NTHR) {
                    int ixj = i ^ j;
                    if (ixj > i) {
                        ull as = sb[i], bs = sb[ixj];
                        int ai = si[i], bi2 = si[ixj];
                        bool up = ((i & sz) == 0);
                        bool aB = before_key(as, ai, bs, bi2);
                        bool sw = up ? (!aB) : aB;
                        if (sw) { sb[i] = bs; sb[ixj] = as; si[i] = bi2; si[ixj] = ai; }
                    }
                }
                __syncthreads();
            }
        }
        for (int i = t; i < PRE; i += NTHR) {
            order1[i] = si[i];
            score_s[i] = __longlong_as_double((long long)sb[i]);
        }
    }
    g.sync();

    // ---------------- P7: dmat tiles + comp accumulation ----------------
    {
        ull (*A)[65] = (ull (*)[65])smem;
        ull (*B)[65] = (ull (*)[65])(smem + 16 * 65 * 8);
        for (int vt = b; vt < 1024; vt += GRID_BLOCKS) {
            int bi = vt & 31, bj = vt >> 5;
            dmat_tile(bi, bj, t, packed, order1, e_count, e_label, dmat, comp, A, B);
            __syncthreads();
        }
    }
    g.sync();

    // ---------------- P8: coef (blocks 0..499), eci inline ----------------
    if (b < PRE) {
        int col = b;
        double m = 1e300;
        for (int i = t; i < PRE; i += NTHR) {
            float d = dmat[i * PRE + col];
            double cc = (double)comp[i];
            double v;
            if (d != 0.0f) {
                double dd = (double)d;
                v = exp(-(dd * dd - cc * cc) * 0.5);
            } else {
                v = exp(cc * cc * 0.5);
            }
            m = fmin(m, v);
        }
        for (int off = 32; off > 0; off >>= 1) m = fmin(m, __shfl_down(m, off));
        double* dred = (double*)smem;              // [4]
        if (lane == 0) dred[wv] = m;
        __syncthreads();
        if (t == 0) {
            m = fmin(fmin(dred[0], dred[1]), fmin(dred[2], dred[3]));
            double s = score_s[col] * m;
            if (s < 0.05) s = 0.0;
            ns[col] = s;
        }
    }
    g.sync();

    // ---------------- P9: sort2 (block 0), emit scores/labels/final_e ----------------
    if (b == 0) {
        ull* sb = (ull*)smem;
        int* si = (int*)(smem + 4096);
        for (int i = t; i < 512; i += NTHR) {
            sb[i] = (i < PRE) ? (ull)__double_as_longlong(ns[i]) : 0ull;
            si[i] = i;
        }
        __syncthreads();
        for (int sz = 2; sz <= 512; sz <<= 1) {
            for (int j = sz >> 1; j > 0; j >>= 1) {
                for (int i = t; i < 512; i += NTHR) {
                    int ixj = i ^ j;
                    if (ixj > i) {
                        ull as = sb[i], bs = sb[ixj];
                        int ai = si[i], bi2 = si[ixj];
                        bool up = ((i & sz) == 0);
                        bool aB = before_key(as, ai, bs, bi2);
                        bool sw = up ? (!aB) : aB;
                        if (sw) { sb[i] = bs; sb[ixj] = as; si[i] = bi2; si[ixj] = ai; }
                    }
                }
                __syncthreads();
            }
        }
        for (int i = t; i < MAXI; i += NTHR) {
            double s = __longlong_as_double((long long)sb[i]);
            int e = order1[si[i]];
            out[i] = (float)s;
            out[MAXI + i] = (float)e_label[e];
            final_e[i] = e;
        }
    }
    g.sync();

    // ---------------- P10: upsample + threshold + bbox ----------------
    {
        int* sxm = (int*)smem;
        int* sxM = (int*)(smem + 16);
        int* sym = (int*)(smem + 32);
        int* syM = (int*)(smem + 48);
        for (int vb = b; vb < UPS_BLOCKS * MAXI; vb += GRID_BLOCKS) {
            int f = vb / UPS_BLOCKS;
            int ub = vb % UPS_BLOCKS;
            int e = final_e[f];
            const float* fm = seg + (size_t)e_gidx[e] * HW;
            float* obase = out + 200 + (size_t)f * OPIX;
            int xmin = 1 << 20, xmax = -1, ymin = 1 << 20, ymax = -1;
            int base = ub * GROUPS_PER_BLOCK + t;
            #pragma unroll 4
            for (int k = 0; k < UPS_ITERS; k++) {
                int p = base + k * 256;
                int oy = p / (OW / 4);
                int gx = p - oy * (OW / 4);
                float iny = (float)oy * 0.25f - 0.375f;
                int y0 = (int)floorf(iny);
                float fy = iny - (float)y0;
                int y0c = max(y0, 0), y1c = min(y0 + 1, FH - 1);
                int xm = max(gx - 1, 0), xp = min(gx + 1, FW - 1);
                const float* r0 = fm + y0c * FW;
                const float* r1 = fm + y1c * FW;
                float am = r0[xm], a0 = r0[gx], ap = r0[xp];
                float bm = r1[xm], b0 = r1[gx], bp = r1[xp];
                float gy = 1.0f - fy;
                float vm = __fadd_rn(__fmul_rn(am, gy), __fmul_rn(bm, fy));
                float v0 = __fadd_rn(__fmul_rn(a0, gy), __fmul_rn(b0, fy));
                float vp = __fadd_rn(__fmul_rn(ap, gy), __fmul_rn(bp, fy));
                float o0 = __fadd_rn(__fmul_rn(vm, 0.375f), __fmul_rn(v0, 0.625f));
                float o1 = __fadd_rn(__fmul_rn(vm, 0.125f), __fmul_rn(v0, 0.875f));
                float o2 = __fadd_rn(__fmul_rn(v0, 0.875f), __fmul_rn(vp, 0.125f));
                float o3 = __fadd_rn(__fmul_rn(v0, 0.625f), __fmul_rn(vp, 0.375f));
                bool m0 = o0 > 0.5f, m1 = o1 > 0.5f, m2 = o2 > 0.5f, m3 = o3 > 0.5f;
                float4 w;
                w.x = m0 ? 1.0f : 0.0f;
                w.y = m1 ? 1.0f : 0.0f;
                w.z = m2 ? 1.0f : 0.0f;
                w.w = m3 ? 1.0f : 0.0f;
                *(float4*)(obase + (size_t)p * 4) = w;
                if (m0 | m1 | m2 | m3) {
                    int ox0 = gx * 4;
                    ymin = min(ymin, oy);
                    ymax = max(ymax, oy);
                    int lo = m0 ? 0 : (m1 ? 1 : (m2 ? 2 : 3));
                    int hi = m3 ? 3 : (m2 ? 2 : (m1 ? 1 : 0));
                    xmin = min(xmin, ox0 + lo);
                    xmax = max(xmax, ox0 + hi);
                }
            }
            for (int off = 32; off > 0; off >>= 1) {
                xmin = min(xmin, __shfl_down(xmin, off));
                xmax = max(xmax, __shfl_down(xmax, off));
                ymin = min(ymin, __shfl_down(ymin, off));
                ymax = max(ymax, __shfl_down(ymax, off));
            }
            if (lane == 0) { sxm[wv] = xmin; sxM[wv] = xmax; sym[wv] = ymin; syM[wv] = ymax; }
            __syncthreads();
            if (t == 0) {
                int mnx = min(min(sxm[0], sxm[1]), min(sxm[2], sxm[3]));
                int mxx = max(max(sxM[0], sxM[1]), max(sxM[2], sxM[3]));
                int mny = min(min(sym[0], sym[1]), min(sym[2], sym[3]));
                int mxy = max(max(syM[0], syM[1]), max(syM[2], syM[3]));
                if (mxx >= 0) {
                    atomicMin(&boxes_i[f * 4 + 0], mnx);
                    atomicMin(&boxes_i[f * 4 + 1], mny);
                    atomicMax(&boxes_i[f * 4 + 2], mxx);
                    atomicMax(&boxes_i[f * 4 + 3], mxy);
                }
            }
            __syncthreads();   // sxm reused next vb iteration
        }
    }
    g.sync();

    // ---------------- P11: boxes finalize (block 0) ----------------
    if (b == 0 && t < MAXI) {
        float sc = out[t];
        float mlt = (sc > 0.0f) ? 1.0f : 0.0f;
        size_t base = 200 + (size_t)MAXI * OPIX;
        out[base + t * 4 + 0] = (float)boxes_i[t * 4 + 0] * mlt;
        out[base + t * 4 + 1] = (float)boxes_i[t * 4 + 1] * mlt;
        out[base + t * 4 + 2] = (float)boxes_i[t * 4 + 2] * mlt;
        out[base + t * 4 + 3] = (float)boxes_i[t * 4 + 3] * mlt;
    }
}

extern "C" void kernel_launch(void* const* d_in, const int* in_sizes, int n_in,
                              void* d_out, int out_size, void* d_ws, size_t ws_size,
                              hipStream_t stream) {
    const float* cate = (const float*)d_in[0];
    const float* seg  = (const float*)d_in[1];
    float* out = (float*)d_out;
    char* ws = (char*)d_ws;

    void* args[] = { (void*)&cate, (void*)&seg, (void*)&out, (void*)&ws };
    hipLaunchCooperativeKernel((const void*)mega, dim3(GRID_BLOCKS), dim3(NTHR),
                               args, 0, stream);
}